// Round 4
// baseline (7831.424 us; speedup 1.0000x reference)
//
#include <hip/hip_runtime.h>

// SentimentAnalyzer: 2-layer (fake-)bidirectional GRU, S=400 B=128 H=512.
// v4: operand-swapped MFMA (A=Whh, B=h) so lane=batch in D. h repacked to
// B-frag store layout in-register (shfl_xor+selects) -> 2 coalesced dwordx4
// sc-stores. Counted vmcnt(6) publish (gi prefetch NOT in drain). Per-wave
// flags, no __syncthreads in the loop. Biases r/z/in folded into GEMM.

typedef unsigned int u32;
typedef unsigned short u16;
typedef __attribute__((ext_vector_type(8))) _Float16 f16x8;
typedef __attribute__((ext_vector_type(4))) float f32x4;
typedef __attribute__((ext_vector_type(16))) float f32x16;
typedef __attribute__((ext_vector_type(4))) u32 u32x4;

#define AS1 __attribute__((address_space(1)))
#define AS3 __attribute__((address_space(3)))

__device__ __forceinline__ void gl_lds16(const void* g, void* l) {
  __builtin_amdgcn_global_load_lds((AS1 void*)g, (AS3 void*)l, 16, 0, 0);
}
__device__ __forceinline__ u16 f2h(float f) {
  _Float16 h = (_Float16)f;
  return __builtin_bit_cast(u16, h);
}
__device__ __forceinline__ u32 pack2(float a, float b) {
  return (u32)f2h(a) | ((u32)f2h(b) << 16);
}
__device__ __forceinline__ float sigm(float x) {
  x = fminf(fmaxf(x, -30.f), 30.f);
  return 1.f / (1.f + __expf(-x));
}
__device__ __forceinline__ float tanh_(float x) {
  x = fminf(fmaxf(x, -15.f), 15.f);
  float e = __expf(2.f * x);
  return (e - 1.f) / (e + 1.f);
}
__device__ __forceinline__ f32x16 mfma32(f16x8 a, f16x8 b, f32x16 c) {
  return __builtin_amdgcn_mfma_f32_32x32x16_f16(a, b, c, 0, 0, 0);
}
// L2-bypass (coherence-point) ops: sc0 sc1.
__device__ __forceinline__ f16x8 load_cc(const u16* sbase, u32 voff) {
  f16x8 r;
  asm volatile("global_load_dwordx4 %0, %1, %2 sc0 sc1"
               : "=v"(r) : "v"(voff), "s"(sbase) : "memory");
  return r;
}
__device__ __forceinline__ void store_cc128(u16* sbase, u32 voff, u32x4 v) {
  asm volatile("global_store_dwordx4 %0, %1, %2 sc0 sc1"
               :: "v"(voff), "v"(v), "s"(sbase) : "memory");
}
__device__ __forceinline__ void store_cc32(u32* sbase, u32 voff, u32 val) {
  asm volatile("global_store_dword %0, %1, %2 sc0 sc1"
               :: "v"(voff), "v"(val), "s"(sbase) : "memory");
}
__device__ __forceinline__ void wait_vm0() {
  asm volatile("s_waitcnt vmcnt(0)" ::: "memory");
}

// ---------------- pack kernels ----------------
__global__ __launch_bounds__(256) void pack_wih(const float* __restrict__ W,
                                                u16* __restrict__ out, int K, int Kp, int total) {
  int idx = blockIdx.x * 256 + threadIdx.x;
  if (idx >= total) return;
  int n = idx / Kp, k = idx - n * Kp;
  out[idx] = (k < K) ? f2h(W[(size_t)n * K + k]) : (u16)0;
}

// Whh frag pack (serves as MFMA A-operand now; layout unchanged):
// [dc(32)][g(3)][kt(32)][l(64)][e(8)] = Whh[d][g*512+c*32+(l&31)][kt*16+(l>>5)*8+e]
__global__ __launch_bounds__(256) void pack_whh(const float* __restrict__ W,
                                                u16* __restrict__ out) {
  int idx = blockIdx.x * 256 + threadIdx.x;  // 196608 total, 8 u16 each
  int l = idx & 63;
  int kt = (idx >> 6) & 31;
  int rest = idx >> 11;
  int g = rest % 3, dc = rest / 3;
  int d = dc >> 4, c = dc & 15;
  int row = g * 512 + c * 32 + (l & 31);
  int k0 = kt * 16 + (l >> 5) * 8;
  const float* src = W + ((size_t)d * 1536 + row) * 512 + k0;
  u32* o = (u32*)(out + (size_t)idx * 8);
#pragma unroll
  for (int e2 = 0; e2 < 4; ++e2) o[e2] = pack2(src[2 * e2], src[2 * e2 + 1]);
}

// biasG[3072]: col=d*1536+g*512+j: g0: bihr+bhhr, g1: bihz+bhhz, g2: bihn.
// bhnG[1024]: d*512+j = bhh_n.
__global__ __launch_bounds__(256) void pack_biasg(const float* __restrict__ bih,
                                                  const float* __restrict__ bhh,
                                                  float* __restrict__ biasG,
                                                  float* __restrict__ bhnG) {
  int idx = blockIdx.x * 256 + threadIdx.x;  // 4096
  if (idx < 3072) {
    int d = idx / 1536, rest = idx - d * 1536;
    int g = rest >> 9, j = rest & 511;
    float v;
    if (g == 0) v = bih[d * 1536 + j] + bhh[d * 1536 + j];
    else if (g == 1) v = bih[d * 1536 + 512 + j] + bhh[d * 1536 + 512 + j];
    else v = bih[d * 1536 + 1024 + j];
    biasG[idx] = v;
  } else {
    int k = idx - 3072;
    int d = k >> 9, j = k & 511;
    bhnG[k] = bhh[d * 1536 + 1024 + j];
  }
}

__global__ __launch_bounds__(256) void gather_emb(const int* __restrict__ X,
                                                  const float* __restrict__ emb,
                                                  u32* __restrict__ out, int t0, int total) {
  int idx = blockIdx.x * 256 + threadIdx.x;
  if (idx >= total) return;
  int r = idx / 160, kp = idx - r * 160;
  int k = kp * 2;
  int tok = X[t0 * 128 + r];
  float v0 = (k < 300) ? emb[(size_t)tok * 300 + k] : 0.f;
  float v1 = (k < 299) ? emb[(size_t)tok * 300 + k + 1] : 0.f;
  out[idx] = pack2(v0, v1);
}

// giP pack index for C[grow][col] (new lane=batch orientation):
__device__ __forceinline__ size_t gip_idx(int t_rel, int grow_b, int col) {
  int dd = (col >= 1536) ? 1 : 0;
  int cc2 = col - dd * 1536;
  int g = cc2 >> 9, ch = (cc2 >> 5) & 15, jj = cc2 & 31;
  int wA = grow_b >> 5, lb = grow_b & 31;
  int l5 = (jj >> 2) & 1;
  int lt = lb | (l5 << 5);
  int r = (jj & 3) | ((jj >> 3) << 2);
  int n2 = g * 2 + (r >> 3), e = r & 7;
  return ((((size_t)t_rel * 2 + dd) * 16 + ch) * 4 + wA) * 3072 + (size_t)n2 * 512 + lt * 8 + e;
}

// ---- layer-0 GEMM: giP = embC[M][320] * B0p[3072][320]^T + biasG ----
__global__ __launch_bounds__(256) void gemm_f16(const u16* __restrict__ A,
                                                const u16* __restrict__ B,
                                                const float* __restrict__ biasG,
                                                u16* __restrict__ giP, int K) {
  __shared__ u16 As[4096];
  __shared__ u16 Bs[4096];
  const int tid = threadIdx.x;
  const int w = tid >> 6, l = tid & 63;
  const long m0 = (long)blockIdx.y << 7;
  const long n0 = (long)blockIdx.x << 7;
  const int wm = w >> 1, wn = w & 1;
  f32x4 acc[4][4] = {};

  const int srow = w * 16 + (l >> 2);
  const int scol = (l & 3) * 8;
  const u16* ga = A + (m0 + srow) * K + scol;
  const u16* gb = B + (n0 + srow) * K + scol;
  u16* lA = &As[w * 512];
  u16* lB = &Bs[w * 512];

  for (int k0 = 0; k0 < K; k0 += 32) {
    gl_lds16(ga + k0, lA);
    gl_lds16(ga + 64 * K + k0, lA + 2048);
    gl_lds16(gb + k0, lB);
    gl_lds16(gb + 64 * K + k0, lB + 2048);
    __syncthreads();
    f16x8 af[4], bf[4];
#pragma unroll
    for (int mi = 0; mi < 4; ++mi)
      af[mi] = *(const f16x8*)&As[(wm * 64 + mi * 16 + (l & 15)) * 32 + ((l >> 4) & 3) * 8];
#pragma unroll
    for (int ni = 0; ni < 4; ++ni)
      bf[ni] = *(const f16x8*)&Bs[(wn * 64 + ni * 16 + (l & 15)) * 32 + ((l >> 4) & 3) * 8];
#pragma unroll
    for (int mi = 0; mi < 4; ++mi)
#pragma unroll
      for (int ni = 0; ni < 4; ++ni)
        acc[mi][ni] = __builtin_amdgcn_mfma_f32_16x16x32_f16(af[mi], bf[ni], acc[mi][ni], 0, 0, 0);
    __syncthreads();
  }
  const int crow = wm * 64 + ((l >> 4) << 2);
  const int ccol = wn * 64 + (l & 15);
#pragma unroll
  for (int mi = 0; mi < 4; ++mi)
#pragma unroll
    for (int ni = 0; ni < 4; ++ni)
#pragma unroll
      for (int i = 0; i < 4; ++i) {
        int grow = (int)m0 + crow + mi * 16 + i;
        int col = (int)n0 + ccol + ni * 16;
        giP[gip_idx(grow >> 7, grow & 127, col)] = f2h(acc[mi][ni][i] + biasG[col]);
      }
}

// ---- layer-1 GEMM: A read directly from y0P frag-pack (no A-LDS) ----
__global__ __launch_bounds__(256) void gemm_l1(const u16* __restrict__ y0P,
                                               const u16* __restrict__ B,
                                               const float* __restrict__ biasG,
                                               u16* __restrict__ giP, int t0) {
  __shared__ u16 Bs[4096];
  const int tid = threadIdx.x;
  const int w = tid >> 6, l = tid & 63;
  const long m0 = (long)blockIdx.y << 7;
  const long n0 = (long)blockIdx.x << 7;
  const int wm = w >> 1, wn = w & 1;
  const int K = 1024;
  f32x4 acc[4][4] = {};

  const int srow = w * 16 + (l >> 2);
  const int scol = (l & 3) * 8;
  const u16* gb = B + (n0 + srow) * K + scol;
  u16* lB = &Bs[w * 512];

  for (int k0 = 0; k0 < K; k0 += 32) {
    gl_lds16(gb + k0, lB);
    gl_lds16(gb + 64 * K + k0, lB + 2048);
    __syncthreads();
    f16x8 af[4], bf[4];
    const int k = k0 + ((l >> 4) & 3) * 8;
    const int dk = k >> 9, ktg = (k >> 4) & 31, l5A = (k >> 3) & 1;
#pragma unroll
    for (int mi = 0; mi < 4; ++mi) {
      int row = (int)m0 + wm * 64 + mi * 16 + (l & 15);
      int t = t0 + (row >> 7), b = row & 127;
      int wA = b >> 5, l31 = b & 31;
      size_t idx = (((((size_t)t * 2 + dk) * 32 + ktg) * 4 + wA) * 64 + (l31 | (l5A << 5))) * 8;
      af[mi] = *(const f16x8*)(y0P + idx);
    }
#pragma unroll
    for (int ni = 0; ni < 4; ++ni)
      bf[ni] = *(const f16x8*)&Bs[(wn * 64 + ni * 16 + (l & 15)) * 32 + ((l >> 4) & 3) * 8];
#pragma unroll
    for (int mi = 0; mi < 4; ++mi)
#pragma unroll
      for (int ni = 0; ni < 4; ++ni)
        acc[mi][ni] = __builtin_amdgcn_mfma_f32_16x16x32_f16(af[mi], bf[ni], acc[mi][ni], 0, 0, 0);
    __syncthreads();
  }
  const int crow = wm * 64 + ((l >> 4) << 2);
  const int ccol = wn * 64 + (l & 15);
#pragma unroll
  for (int mi = 0; mi < 4; ++mi)
#pragma unroll
    for (int ni = 0; ni < 4; ++ni)
#pragma unroll
      for (int i = 0; i < 4; ++i) {
        int grow = (int)m0 + crow + mi * 16 + i;
        int col = (int)n0 + ccol + ni * 16;
        giP[gip_idx(grow >> 7, grow & 127, col)] = f2h(acc[mi][ni][i] + biasG[col]);
      }
}

// ---------------- persistent GRU recurrence (one layer, both dirs) ----------------
// 32 blocks: d=bid>>4, c=bid&15 (32 h-cols). 4 independent waves x 32 batches.
// MFMA: acc = Whh_frag(A, LDS) x h_frag(B, hp loads); D: lane=batch, reg=gatecol.
// hp ring: 4 slots x [d2][w4][ktg32][l64][e8] f16. flags[d][slot][64] per-wave.
__global__ __launch_bounds__(256, 1) void gru_layer(const u16* __restrict__ gi,
                                                    const u16* __restrict__ WhhP,
                                                    const float* __restrict__ bhnG,
                                                    float* __restrict__ hf,
                                                    u16* __restrict__ hp,
                                                    u16* __restrict__ y0,
                                                    u32* __restrict__ flags,
                                                    int t0, int TC) {
  const int bid = blockIdx.x;
  const int d = bid >> 4, c = bid & 15;
  const int tid = threadIdx.x;
  const int w = tid >> 6, l = tid & 63;
  const int l31 = l & 31, l5 = l >> 5;

  __shared__ u16 Wl[49152];  // [g3][kt32][l64][e8], 96 KiB

  {  // stage this block's Whh slice
    const u32x4* src = (const u32x4*)(WhhP + (size_t)(d * 16 + c) * 49152);
    u32x4* dst = (u32x4*)Wl;
#pragma unroll
    for (int i = 0; i < 24; ++i) dst[i * 256 + tid] = src[i * 256 + tid];
  }

  float bhnv[16], hreg[16];
#pragma unroll
  for (int r = 0; r < 16; ++r) {
    int col = c * 32 + (r & 3) + 8 * (r >> 2) + 4 * l5;
    bhnv[r] = bhnG[d * 512 + col];
    hreg[r] = hf[((size_t)d * 128 + w * 32 + l31) * 512 + col];
  }
  __syncthreads();

  // prefetch gi(t0)
  f16x8 giv[6];
  {
    const u16* gp = gi + (((size_t)d * 16 + c) * 4 + w) * 3072 + l * 8;
#pragma unroll
    for (int n2 = 0; n2 < 6; ++n2) giv[n2] = *(const f16x8*)(gp + n2 * 512);
  }
  wait_vm0();  // clean vmem queue before counted waits

  const u32 aoffbase = (u32)((d * 4 + w) * 32768 + l * 16);  // bytes
  const u32 foff = (u32)(l * 4);

  for (int t = t0; t < t0 + TC; ++t) {
    // ---- poll flags(t): 64 per-wave producer flags of this direction ----
    {
      const u32* fb = flags + (size_t)(d * 4 + (t & 3)) * 64;
      for (;;) {
        u32 v;
        asm volatile("global_load_dword %0, %1, %2 sc0 sc1\n\ts_waitcnt vmcnt(0)"
                     : "=v"(v) : "v"(foff), "s"(fb) : "memory");
        if (__all((int)(v >= (u32)t))) break;
      }
    }

    // ---- issue all 32 h-frag loads (L2-bypass) ----
    const u16* hrb = hp + (size_t)(t & 3) * 131072;
    f16x8 a[32];
#pragma unroll
    for (int kt = 0; kt < 32; ++kt) a[kt] = load_cc(hrb, aoffbase + (u32)kt * 1024u);

    f32x16 accR = {}, accZ = {}, accN = {};
#pragma unroll
    for (int g4 = 0; g4 < 8; ++g4) {
      switch (g4) {
        case 0: asm volatile("s_waitcnt vmcnt(28)" ::: "memory"); break;
        case 1: asm volatile("s_waitcnt vmcnt(24)" ::: "memory"); break;
        case 2: asm volatile("s_waitcnt vmcnt(20)" ::: "memory"); break;
        case 3: asm volatile("s_waitcnt vmcnt(16)" ::: "memory"); break;
        case 4: asm volatile("s_waitcnt vmcnt(12)" ::: "memory"); break;
        case 5: asm volatile("s_waitcnt vmcnt(8)" ::: "memory"); break;
        case 6: asm volatile("s_waitcnt vmcnt(4)" ::: "memory"); break;
        default: asm volatile("s_waitcnt vmcnt(0)" ::: "memory"); break;
      }
      __builtin_amdgcn_sched_barrier(0);
#pragma unroll
      for (int kk = 0; kk < 4; ++kk) {
        int kt = g4 * 4 + kk;
        f16x8 b0 = *(const f16x8*)&Wl[(0 * 32 + kt) * 512 + l * 8];
        f16x8 b1 = *(const f16x8*)&Wl[(1 * 32 + kt) * 512 + l * 8];
        f16x8 b2 = *(const f16x8*)&Wl[(2 * 32 + kt) * 512 + l * 8];
        accR = mfma32(b0, a[kt], accR);
        accZ = mfma32(b1, a[kt], accZ);
        accN = mfma32(b2, a[kt], accN);
      }
    }

    // ---- per-lane epilogue (lane=batch, reg=gatecol) ----
    float hn[16];
#pragma unroll
    for (int r = 0; r < 16; ++r) {
      float gr = (float)giv[r >> 3][r & 7];
      float gz = (float)giv[2 + (r >> 3)][r & 7];
      float gn = (float)giv[4 + (r >> 3)][r & 7];
      float rr = sigm(gr + accR[r]);
      float zz = sigm(gz + accZ[r]);
      float nn = tanh_(gn + rr * (accN[r] + bhnv[r]));
      hn[r] = (1.f - zz) * nn + zz * hreg[r];
      hreg[r] = hn[r];
    }

    // ---- in-register repack to B-frag store layout ----
    u32 Wpk[4][2];
#pragma unroll
    for (int a2 = 0; a2 < 4; ++a2)
#pragma unroll
      for (int p = 0; p < 2; ++p)
        Wpk[a2][p] = pack2(hn[4 * a2 + 2 * p], hn[4 * a2 + 2 * p + 1]);
    u32 X[2][2], S[2][2], Y[2][2];
#pragma unroll
    for (int kt = 0; kt < 2; ++kt)
#pragma unroll
      for (int p = 0; p < 2; ++p) {
        X[kt][p] = l5 ? Wpk[2 * kt + 1][p] : Wpk[2 * kt][p];
        S[kt][p] = l5 ? Wpk[2 * kt][p] : Wpk[2 * kt + 1][p];
      }
#pragma unroll
    for (int kt = 0; kt < 2; ++kt)
#pragma unroll
      for (int p = 0; p < 2; ++p)
        Y[kt][p] = (u32)__shfl_xor((int)S[kt][p], 32);

    u16* hwb = hp + (size_t)((t + 1) & 3) * 131072;
#pragma unroll
    for (int kt = 0; kt < 2; ++kt) {
      u32x4 wv;
      wv[0] = l5 ? Y[kt][0] : X[kt][0];
      wv[1] = l5 ? Y[kt][1] : X[kt][1];
      wv[2] = l5 ? X[kt][0] : Y[kt][0];
      wv[3] = l5 ? X[kt][1] : Y[kt][1];
      u32 hoff = (u32)((((d * 4 + w) * 32 + (c * 2 + kt)) * 64 + l) * 16);
      store_cc128(hwb, hoff, wv);
      if (y0) {
        size_t yi = ((((size_t)t * 2 + d) * 32 + (c * 2 + kt)) * 4 + w) * 512 + (size_t)l * 8;
        *(u32x4*)(y0 + yi) = wv;
      }
    }

    // ---- gi prefetch for t+1 (issued AFTER stores; not in the drain) ----
    f16x8 gt[6];
    {
      int rel = t + 1 - t0;
      if (rel >= TC) rel = TC - 1;
      const u16* gp = gi + (((size_t)rel * 2 + d) * 16 + c) * 12288 + (size_t)w * 3072 + l * 8;
#pragma unroll
      for (int n2 = 0; n2 < 6; ++n2) gt[n2] = *(const f16x8*)(gp + n2 * 512);
    }

    // ---- publish: wait only the hp stores (in-order retire), per-wave flag ----
    asm volatile("s_waitcnt vmcnt(6)" ::: "memory");
    if (l == 0) {
      u32* fw = flags + (size_t)(d * 4 + ((t + 1) & 3)) * 64;
      store_cc32(fw, (u32)((c * 4 + w) * 4), (u32)(t + 1));
    }
#pragma unroll
    for (int n2 = 0; n2 < 6; ++n2) giv[n2] = gt[n2];
  }

#pragma unroll
  for (int r = 0; r < 16; ++r) {
    int col = c * 32 + (r & 3) + 8 * (r >> 2) + 4 * l5;
    hf[((size_t)d * 128 + w * 32 + l31) * 512 + col] = hreg[r];
  }
  wait_vm0();
}

// ---------------- classifier ----------------
__global__ __launch_bounds__(128) void classify(const float* __restrict__ hf,
                                                const float* __restrict__ Ws,
                                                const float* __restrict__ bs,
                                                float* __restrict__ out) {
  int b = threadIdx.x;
  float l0 = bs[0], l1 = bs[1];
#pragma unroll 8
  for (int j = 0; j < 512; ++j) {
    float v = hf[b * 512 + j];
    l0 = fmaf(v, Ws[j], l0);
    l1 = fmaf(v, Ws[1024 + j], l1);
  }
#pragma unroll 8
  for (int j = 0; j < 512; ++j) {
    float v = hf[(128 + b) * 512 + j];
    l0 = fmaf(v, Ws[512 + j], l0);
    l1 = fmaf(v, Ws[1536 + j], l1);
  }
  float m = fmaxf(l0, l1);
  float lse = m + __logf(__expf(l0 - m) + __expf(l1 - m));
  out[b * 2] = l0 - lse;
  out[b * 2 + 1] = l1 - lse;
}

extern "C" void kernel_launch(void* const* d_in, const int* in_sizes, int n_in,
                              void* d_out, int out_size, void* d_ws, size_t ws_size,
                              hipStream_t stream) {
  const int* X = (const int*)d_in[0];
  const float* emb = (const float*)d_in[1];
  const float* Wih0 = (const float*)d_in[2];
  const float* Whh0 = (const float*)d_in[3];
  const float* bih0 = (const float*)d_in[4];
  const float* bhh0 = (const float*)d_in[5];
  const float* Wih1 = (const float*)d_in[6];
  const float* Whh1 = (const float*)d_in[7];
  const float* bih1 = (const float*)d_in[8];
  const float* bhh1 = (const float*)d_in[9];
  const float* Ws = (const float*)d_in[10];
  const float* bs = (const float*)d_in[11];
  float* out = (float*)d_out;

  const int S = 400, B = 128;
  auto need = [&](int nc) -> size_t {
    size_t TC = (size_t)S / nc, R = TC * B;
    size_t sz = 0;
    sz += R * 3072 * 2;              // giPack
    sz += (size_t)S * B * 1024 * 2;  // y0P
    sz += R * 320 * 2;               // embC
    sz += (size_t)3072 * 320 * 2;    // B0p
    sz += (size_t)3072 * 1024 * 2;   // B1p
    sz += 2 * (size_t)1572864 * 2;   // WhhP x2
    sz += 2 * (size_t)4096 * 4;      // biasG/bhnG x2
    sz += 2 * (size_t)131072 * 4;    // hf x2
    sz += 2 * (size_t)524288 * 2;    // hp x2 (4-slot ring)
    sz += 65536;
    return sz;
  };
  int nc = 16;
  if (need(1) <= ws_size) nc = 1;
  else if (need(2) <= ws_size) nc = 2;
  else if (need(4) <= ws_size) nc = 4;
  else if (need(8) <= ws_size) nc = 8;
  const int TC = S / nc;
  const size_t R = (size_t)TC * B;

  char* p = (char*)d_ws;
  auto alloc = [&](size_t bytes) {
    char* q = p;
    p += (bytes + 255) & ~(size_t)255;
    return q;
  };
  u16* giPack = (u16*)alloc(R * 3072 * 2);
  u16* y0P = (u16*)alloc((size_t)S * B * 1024 * 2);
  u16* embC = (u16*)alloc(R * 320 * 2);
  u16* B0p = (u16*)alloc((size_t)3072 * 320 * 2);
  u16* B1p = (u16*)alloc((size_t)3072 * 1024 * 2);
  u16* WhhP0 = (u16*)alloc((size_t)1572864 * 2);
  u16* WhhP1 = (u16*)alloc((size_t)1572864 * 2);
  float* biasG0 = (float*)alloc(3072 * 4);
  float* bhnG0 = (float*)alloc(1024 * 4);
  float* biasG1 = (float*)alloc(3072 * 4);
  float* bhnG1 = (float*)alloc(1024 * 4);
  float* hf0 = (float*)alloc(131072 * 4);
  float* hf1 = (float*)alloc(131072 * 4);
  u16* hp0 = (u16*)alloc(524288 * 2);
  u16* hp1 = (u16*)alloc(524288 * 2);
  u32* flags0 = (u32*)alloc(4096);
  u32* flags1 = (u32*)alloc(4096);

  hipMemsetAsync(hf0, 0, 131072 * 4, stream);
  hipMemsetAsync(hf1, 0, 131072 * 4, stream);
  hipMemsetAsync(hp0, 0, 524288 * 2, stream);
  hipMemsetAsync(hp1, 0, 524288 * 2, stream);
  hipMemsetAsync(flags0, 0, 4096, stream);
  hipMemsetAsync(flags1, 0, 4096, stream);

  pack_wih<<<3840, 256, 0, stream>>>(Wih0, B0p, 300, 320, 3072 * 320);
  pack_wih<<<12288, 256, 0, stream>>>(Wih1, B1p, 1024, 1024, 3072 * 1024);
  pack_whh<<<768, 256, 0, stream>>>(Whh0, WhhP0);
  pack_whh<<<768, 256, 0, stream>>>(Whh1, WhhP1);
  pack_biasg<<<16, 256, 0, stream>>>(bih0, bhh0, biasG0, bhnG0);
  pack_biasg<<<16, 256, 0, stream>>>(bih1, bhh1, biasG1, bhnG1);

  dim3 gg(24, (unsigned)(R / 128));
  for (int cix = 0; cix < nc; ++cix) {
    int t0 = cix * TC;
    int total = (int)(R * 160);
    gather_emb<<<(total + 255) / 256, 256, 0, stream>>>(X, emb, (u32*)embC, t0, total);
    gemm_f16<<<gg, 256, 0, stream>>>(embC, B0p, biasG0, giPack, 320);
    gru_layer<<<32, 256, 0, stream>>>(giPack, WhhP0, bhnG0, hf0, hp0, y0P, flags0, t0, TC);
  }
  for (int cix = 0; cix < nc; ++cix) {
    int t0 = cix * TC;
    gemm_l1<<<gg, 256, 0, stream>>>(y0P, B1p, biasG1, giPack, t0);
    gru_layer<<<32, 256, 0, stream>>>(giPack, WhhP1, bhnG1, hf1, hp1, (u16*)nullptr, flags1, t0, TC);
  }
  classify<<<1, 128, 0, stream>>>(hf1, Ws, bs, out);
}